// Round 5
// baseline (789.240 us; speedup 1.0000x reference)
//
#include <hip/hip_runtime.h>

// Swin dilated-window cross-attention, MI355X bf16-MFMA implementation.
// Phases: prep -> convg(x) -> gemm<0>(qv,+rope) -> convg(cross) -> gemm<1>(k,+rope)
//         -> attn -> gemm<2>(proj,scatter)
// ws layout: Qbuf 64MB | Kbuf 64MB | Vbuf(transposed per head) 64MB | Obuf 64MB |
//            qv_wt 1MB | k_wt 0.5MB | proj_wt 0.5MB | rope tables 16KB  (~258MB)
// The Obuf region doubles as the bf16 token-order input buffer (xg/crossg) before
// attn overwrites it.
//
// R1: XCD-chunked bn-fastest block order (A-tile L2 reuse) + packed V stores.
// R2: conversion hoisted to streaming pass; GEMM staging via global_load_lds w=16.
//     Result: bank conflicts 8.4M->0, VALUBusy 27->17, but dur only 286->204 us:
//     every K-step still drains vmcnt(0) at the barrier right after issuing loads
//     -> full latency exposed, MfmaUtil 13.9% == pure-MFMA floor / dur.
// R5: (a) 2-phase double-buffered K-loop (T3 minimum recipe): prefetch tile t+1
//     before computing tile t; ONE barrier per K-step; load latency hides under
//     ds_read+MFMA. (b) gather folded into convert (writes token-order bf16, both
//     sides 1KB-contiguous) -> GEMM A addressing fully linear in all modes.

typedef float v4f __attribute__((ext_vector_type(4)));
typedef short short8 __attribute__((ext_vector_type(8)));
typedef unsigned short us4 __attribute__((ext_vector_type(4)));

#define BM 128
#define BN 128

__device__ __forceinline__ unsigned short f2bf(float f) {
  unsigned int u = __builtin_bit_cast(unsigned int, f);
  u += 0x7fffu + ((u >> 16) & 1u);   // round-to-nearest-even
  return (unsigned short)(u >> 16);
}

__device__ __forceinline__ void gload_lds16(const void* g, void* l) {
  __builtin_amdgcn_global_load_lds((const __attribute__((address_space(1))) void*)g,
                                   (__attribute__((address_space(3))) void*)l, 16, 0, 0);
}

// token (g*64+n) -> source/dest pixel index (b*128+i)*128+j  (roll + window + dilation)
__device__ __forceinline__ int tok2pix(int tok) {
  int g = tok >> 6, n = tok & 63;
  int b = g >> 8, rem = g & 255;
  int d = rem & 3, bw = rem >> 2;
  int wh = bw >> 3, ww = bw & 7;
  int ph = n >> 3, pw = n & 7;
  int ii = (wh * 16 + 2 * ph + (d >> 1) + 4) & 127;
  int jj = (ww * 16 + 2 * pw + (d & 1) + 4) & 127;
  return (b * 128 + ii) * 128 + jj;
}

__global__ __launch_bounds__(256) void prep_kernel(
    const float* __restrict__ qv_w, const float* __restrict__ k_w,
    const float* __restrict__ proj_w,
    unsigned short* __restrict__ qv_wt, unsigned short* __restrict__ k_wt,
    unsigned short* __restrict__ proj_wt,
    float* __restrict__ rope_cos, float* __restrict__ rope_sin) {
  int tid = blockIdx.x * 256 + threadIdx.x;
  if (tid < 524288) {                       // qv_wt[c][k] = qv_w[k][c]
    int c = tid >> 9, k = tid & 511;
    qv_wt[tid] = f2bf(qv_w[k * 1024 + c]);
  } else if (tid < 786432) {                // k_wt[c][k] = k_w[k][c]
    int t = tid - 524288;
    int c = t >> 9, k = t & 511;
    k_wt[t] = f2bf(k_w[k * 512 + c]);
  } else if (tid < 1048576) {               // proj_wt[c][k] = proj_w[k][c]
    int t = tid - 786432;
    int c = t >> 9, k = t & 511;
    proj_wt[t] = f2bf(proj_w[k * 512 + c]);
  } else if (tid < 1048576 + 2048) {        // rope tables: [(ph*8+pw)*32 + t]
    int t = tid - 1048576;
    int pos = t >> 5, tt = t & 31;
    int ph = pos >> 3, pw = pos & 7;
    float e = (float)(tt & 15) * (1.0f / 16.0f);
    float inv = powf(10000.0f, -e);
    float ang = (float)(tt < 16 ? ph : pw) * inv;
    rope_cos[t] = cosf(ang);
    rope_sin[t] = sinf(ang);
  }
}

// Streaming fp32 -> bf16 WITH token gather: out[tok][c] = bf16(in[tok2pix(tok)][c]).
// 64 consecutive threads handle one token row: read 2KB contiguous fp32, write 1KB
// contiguous bf16 -> full BW both sides; the GEMM then reads A fully linearly.
__global__ __launch_bounds__(256) void convert_kernel(
    const float* __restrict__ in, unsigned short* __restrict__ out) {
  unsigned int stride = gridDim.x * 256u;
  for (unsigned int i = blockIdx.x * 256u + threadIdx.x; i < 4194304u; i += stride) {
    int tok = (int)(i >> 6), c8 = (int)(i & 63) * 8;
    size_t src = (size_t)tok2pix(tok) * 512 + c8;
    v4f t0 = *(const v4f*)(in + src);
    v4f t1 = *(const v4f*)(in + src + 4);
    short8 w;
    w[0] = (short)f2bf(t0[0]); w[1] = (short)f2bf(t0[1]);
    w[2] = (short)f2bf(t0[2]); w[3] = (short)f2bf(t0[3]);
    w[4] = (short)f2bf(t1[0]); w[5] = (short)f2bf(t1[1]);
    w[6] = (short)f2bf(t1[2]); w[7] = (short)f2bf(t1[3]);
    *(short8*)(out + (size_t)tok * 512 + c8) = w;
  }
}

// MODE 0: A = xg (bf16 token-order), Wt = qv_wt: q->rope*scale->Qbuf, v->Vbuf(T)
// MODE 1: A = crossg (bf16 token-order), Wt = k_wt: rope->Kbuf
// MODE 2: A = Obuf (bf16 token-order), Wt = proj_wt: +bias, scatter fp32 -> d_out
template <int MODE>
__global__ __launch_bounds__(256) void gemm_kernel(
    const unsigned short* __restrict__ Ap, const unsigned short* __restrict__ Wt,
    const float* __restrict__ bias, void* __restrict__ out0,
    void* __restrict__ out1, const float* __restrict__ rope_cos,
    const float* __restrict__ rope_sin) {
  // LDS: double-buffered chunked layout [h=k/8][row ^ h][8 bf16]; conflict-free
  // ds_read_b128 frags. global_load_lds writes chunks linearly; the XOR permutation
  // is baked into each chunk's GLOBAL source row (row^h), LDS dest stays linear.
  __shared__ __attribute__((aligned(16))) unsigned short As[2][4096];
  __shared__ __attribute__((aligned(16))) unsigned short Bs[2][4096];
  int tid = threadIdx.x;

  // Block->tile remap: XCD-chunked (bijective, nwg%8==0) with bn FASTEST inside a
  // chunk, so blocks sharing one A-tile run back-to-back on the SAME XCD (L2 reuse).
  constexpr int NBN = (MODE == 0) ? 8 : 4;           // output col-tiles
  constexpr int NWG = 512 * NBN;
  constexpr int CPX = NWG / 8;                       // chunk per XCD
  int lin = blockIdx.x;
  int wgid = (lin & 7) * CPX + (lin >> 3);
  int bm = wgid / NBN;
  int bn = wgid % NBN;

  int lane = tid & 63, wid = tid >> 6;
  int wm = (wid & 1) * 64, wn = (wid >> 1) * 64;
  int l15 = lane & 15, quad = lane >> 4;

  // Per-thread staging chunk source addresses. 16B chunk c = issue*256 + tid maps
  // to LDS chunk c, which must hold A[(c&127)^h][k0 + h*8 ..] with h = c>>7.
  const unsigned short* pa[2];
  const unsigned short* pb[2];
  int lOff[2];   // LDS element offset of this thread's chunk base (wave-uniform part)
#pragma unroll
  for (int i = 0; i < 2; i++) {
    int c = i * 256 + tid;
    int h = c >> 7, row = (c & 127) ^ h;
    pa[i] = Ap + (size_t)(bm * BM + row) * 512 + h * 8;
    pb[i] = Wt + (size_t)(bn * BN + row) * 512 + h * 8;
    lOff[i] = (i * 256 + wid * 64) * 8;   // wave-uniform base (hardware adds lane*16)
  }

  v4f acc[4][4];
#pragma unroll
  for (int i = 0; i < 4; i++)
#pragma unroll
    for (int j = 0; j < 4; j++) acc[i][j] = (v4f){0.f, 0.f, 0.f, 0.f};

  // prologue: stage tile 0 into buffer 0
#pragma unroll
  for (int i = 0; i < 2; i++) {
    gload_lds16(pa[i], &As[0][lOff[i]]);
    gload_lds16(pb[i], &Bs[0][lOff[i]]);
  }
  __syncthreads();   // drains vmcnt -> tile 0 visible

  int cur = 0;
  for (int t = 0; t < 16; ++t) {
    if (t < 15) {
      int k0 = (t + 1) * 32;
      int nxt = cur ^ 1;
#pragma unroll
      for (int i = 0; i < 2; i++) {
        gload_lds16(pa[i] + k0, &As[nxt][lOff[i]]);
        gload_lds16(pb[i] + k0, &Bs[nxt][lOff[i]]);
      }
    }
    short8 af[4], bfr[4];
#pragma unroll
    for (int i = 0; i < 4; i++)
      af[i] = *(const short8*)(&As[cur][(quad * 128 + ((wm + i * 16 + l15) ^ quad)) << 3]);
#pragma unroll
    for (int j = 0; j < 4; j++)
      bfr[j] = *(const short8*)(&Bs[cur][(quad * 128 + ((wn + j * 16 + l15) ^ quad)) << 3]);
#pragma unroll
    for (int i = 0; i < 4; i++)
#pragma unroll
      for (int j = 0; j < 4; j++)
        acc[i][j] = __builtin_amdgcn_mfma_f32_16x16x32_bf16(af[i], bfr[j], acc[i][j], 0, 0, 0);
    __syncthreads();   // drains next tile's prefetch; protects buf reuse
    cur ^= 1;
  }

  // Epilogue. C/D layout: row = quad*4+reg (A-rows = tokens), col = lane&15 (B-rows = out channel)
#pragma unroll
  for (int j = 0; j < 4; j++) {
    int col = bn * BN + wn + j * 16 + l15;
    float bv = bias[col];
    int which = col >> 9;            // wave-uniform
    int h = (col >> 6) & 7;
    int hd = col & 63;
#pragma unroll
    for (int i = 0; i < 4; i++) {
      int tok0 = bm * BM + wm + i * 16 + quad * 4;
      if (MODE == 0 && which == 1) {
        // V stored transposed: [g][h][hd][n] — 4 consecutive n per lane -> one 8B store
        int g = tok0 >> 6, n0 = tok0 & 63;   // quad*4-aligned, no wrap across r
        us4 wv;
#pragma unroll
        for (int r = 0; r < 4; r++) wv[r] = f2bf(acc[i][j][r] + bv);
        *(us4*)((unsigned short*)out1 + ((((g * 8 + h) * 64 + hd) << 6) + n0)) = wv;
      } else if (MODE == 2) {
#pragma unroll
        for (int r = 0; r < 4; r++)
          ((float*)out0)[(size_t)tok2pix(tok0 + r) * 512 + col] = acc[i][j][r] + bv;
      } else {
        // Q (MODE 0) or K (MODE 1): rope, then store [g][h][n][hd]
#pragma unroll
        for (int r = 0; r < 4; r++) {
          int tok = tok0 + r;
          int g = tok >> 6, n = tok & 63;
          float val = acc[i][j][r] + bv;
          float part = __shfl_xor(val, 1); // rope pair partner (col^1)
          int ti = (n << 5) + (hd >> 1);
          float c = rope_cos[ti], s = rope_sin[ti];
          float o = (hd & 1) ? (part * s + val * c) : (val * c - part * s);
          if (MODE == 0) o *= 0.125f;      // HD^-0.5
          ((unsigned short*)out0)[(((g * 8 + h) * 64 + n) << 6) + hd] = f2bf(o);
        }
      }
    }
  }
}

// One block per (window-group g, head h). N=64 tokens, HD=64.
__global__ __launch_bounds__(256) void attn_kernel(
    const unsigned short* __restrict__ Qbuf, const unsigned short* __restrict__ Kbuf,
    const unsigned short* __restrict__ Vbuf, unsigned short* __restrict__ Obuf) {
  __shared__ __attribute__((aligned(16))) unsigned short Ps[4096]; // P, swizzled chunks
  int bid = blockIdx.x;
  int g = bid >> 3, h = bid & 7;
  int tid = threadIdx.x;
  int lane = tid & 63, w = tid >> 6;
  int l15 = lane & 15, quad = lane >> 4;
  size_t base = ((size_t)(g * 8 + h)) << 12;   // *4096 elems
  const unsigned short* Q = Qbuf + base;       // [n][hd]
  const unsigned short* K = Kbuf + base;       // [n][hd]
  const unsigned short* Vt = Vbuf + base;      // [hd][n]

  // S = (Q*scale,rope) @ (K,rope)^T ; wave w owns q-rows [w*16, w*16+16)
  v4f s[4];
#pragma unroll
  for (int j = 0; j < 4; j++) s[j] = (v4f){0.f, 0.f, 0.f, 0.f};
#pragma unroll
  for (int ki = 0; ki < 2; ki++) {
    short8 aq = *(const short8*)(Q + (w * 16 + l15) * 64 + ki * 32 + quad * 8);
#pragma unroll
    for (int j = 0; j < 4; j++) {
      short8 bk = *(const short8*)(K + (j * 16 + l15) * 64 + ki * 32 + quad * 8);
      s[j] = __builtin_amdgcn_mfma_f32_16x16x32_bf16(aq, bk, s[j], 0, 0, 0);
    }
  }

  // mask: only wh==7 windows; group by ph band (ph<4 | 4..5 | >=6), row-only dependence
  int rem = g & 255;
  bool masked_win = ((rem >> 5) == 7);
  float p[4][4]; // [j][r]
#pragma unroll
  for (int j = 0; j < 4; j++) {
    int m = j * 16 + l15;
    int pm = m >> 3;
    int gm = (int)(pm >= 4) + (int)(pm >= 6);
#pragma unroll
    for (int r = 0; r < 4; r++) {
      int row = w * 16 + quad * 4 + r;
      int pq = row >> 3;
      int gq = (int)(pq >= 4) + (int)(pq >= 6);
      float v = s[j][r];
      if (masked_win && gm != gq) v = -1e9f;
      p[j][r] = v;
    }
  }
  // softmax per row: values live on the 16 lanes of this quad (cols) x 4 j-tiles
#pragma unroll
  for (int r = 0; r < 4; r++) {
    float mx = fmaxf(fmaxf(p[0][r], p[1][r]), fmaxf(p[2][r], p[3][r]));
    mx = fmaxf(mx, __shfl_xor(mx, 1));
    mx = fmaxf(mx, __shfl_xor(mx, 2));
    mx = fmaxf(mx, __shfl_xor(mx, 4));
    mx = fmaxf(mx, __shfl_xor(mx, 8));
    float sum = 0.f;
#pragma unroll
    for (int j = 0; j < 4; j++) { p[j][r] = __expf(p[j][r] - mx); sum += p[j][r]; }
    sum += __shfl_xor(sum, 1);
    sum += __shfl_xor(sum, 2);
    sum += __shfl_xor(sum, 4);
    sum += __shfl_xor(sum, 8);
    float inv = 1.0f / sum;
    int row = w * 16 + quad * 4 + r;
#pragma unroll
    for (int j = 0; j < 4; j++) {
      int m = j * 16 + l15;
      int h8 = m >> 3;
      Ps[((h8 * 64 + (row ^ h8)) << 3) + (m & 7)] = f2bf(p[j][r] * inv);
    }
  }
  __syncthreads();

  // O = P @ V : A = P rows (this wave's), B = Vt (n=hd, k=m)
  v4f o[4];
#pragma unroll
  for (int j = 0; j < 4; j++) o[j] = (v4f){0.f, 0.f, 0.f, 0.f};
#pragma unroll
  for (int ki = 0; ki < 2; ki++) {
    int h8 = ki * 4 + quad;
    short8 ap = *(const short8*)(Ps + ((h8 * 64 + ((w * 16 + l15) ^ h8)) << 3));
#pragma unroll
    for (int j = 0; j < 4; j++) {
      short8 bv = *(const short8*)(Vt + (j * 16 + l15) * 64 + ki * 32 + quad * 8);
      o[j] = __builtin_amdgcn_mfma_f32_16x16x32_bf16(ap, bv, o[j], 0, 0, 0);
    }
  }
#pragma unroll
  for (int j = 0; j < 4; j++) {
    int hd = j * 16 + l15;
#pragma unroll
    for (int r = 0; r < 4; r++) {
      int row = w * 16 + quad * 4 + r;
      Obuf[(size_t)(g * 64 + row) * 512 + h * 64 + hd] = f2bf(o[j][r]);
    }
  }
}

extern "C" void kernel_launch(void* const* d_in, const int* in_sizes, int n_in,
                              void* d_out, int out_size, void* d_ws, size_t ws_size,
                              hipStream_t stream) {
  const float* x      = (const float*)d_in[0];
  const float* cross  = (const float*)d_in[1];
  const float* qv_w   = (const float*)d_in[2];
  const float* qv_b   = (const float*)d_in[3];
  const float* k_w    = (const float*)d_in[4];
  const float* k_b    = (const float*)d_in[5];
  const float* proj_w = (const float*)d_in[6];
  const float* proj_b = (const float*)d_in[7];

  char* ws = (char*)d_ws;
  const size_t MB = 1024 * 1024;
  unsigned short* Qbuf = (unsigned short*)(ws);
  unsigned short* Kbuf = (unsigned short*)(ws + 64 * MB);
  unsigned short* Vbuf = (unsigned short*)(ws + 128 * MB);
  unsigned short* Obuf = (unsigned short*)(ws + 192 * MB);
  unsigned short* qv_wt = (unsigned short*)(ws + 256 * MB);
  unsigned short* k_wt = qv_wt + 1024 * 512;
  unsigned short* proj_wt = k_wt + 512 * 512;
  float* rope_cos = (float*)(proj_wt + 512 * 512);
  float* rope_sin = rope_cos + 2048;
  unsigned short* cvt = Obuf;   // Obuf region is dead until attn -> holds bf16 inputs

  prep_kernel<<<4104, 256, 0, stream>>>(qv_w, k_w, proj_w, qv_wt, k_wt, proj_wt,
                                        rope_cos, rope_sin);
  convert_kernel<<<2048, 256, 0, stream>>>(x, cvt);
  gemm_kernel<0><<<4096, 256, 0, stream>>>(cvt, qv_wt, qv_b, Qbuf, Vbuf,
                                           rope_cos, rope_sin);
  convert_kernel<<<2048, 256, 0, stream>>>(cross, cvt);
  gemm_kernel<1><<<2048, 256, 0, stream>>>(cvt, k_wt, k_b, Kbuf, nullptr,
                                           rope_cos, rope_sin);
  attn_kernel<<<8192, 256, 0, stream>>>(Qbuf, Kbuf, Vbuf, Obuf);
  gemm_kernel<2><<<2048, 256, 0, stream>>>(Obuf, proj_wt, proj_b, d_out, nullptr,
                                           rope_cos, rope_sin);
}

// Round 6
// 666.592 us; speedup vs baseline: 1.1840x; 1.1840x over previous
//
#include <hip/hip_runtime.h>

// Swin dilated-window cross-attention, MI355X bf16-MFMA implementation.
// Phases: prep -> convg(x) -> gemm<0>(qv,+rope) -> convg(cross) -> gemm<1>(k,+rope)
//         -> attn -> gemm<2>(proj,scatter)
// ws layout: Qbuf 64MB | Kbuf 64MB | Vbuf(transposed per head) 64MB | Obuf 64MB |
//            qv_wt 1MB | k_wt 0.5MB | proj_wt 0.5MB | rope tables 16KB  (~258MB)
// The Obuf region doubles as the bf16 token-order input buffer (xg/crossg).
//
// R2: global_load_lds staging (bank conflicts 0, FETCH 4x down) - still 204us.
// R5: 2-phase dbuf - NEUTRAL (200us). Diagnosis: not latency-bound but L2
//     REQUEST-RATE bound: old chunk map put consecutive lanes on consecutive ROWS
//     (1KB stride) -> each staging instr touched 64 distinct cache lines, 16B
//     used each -> 4x request amplification, ~4500cyc/K-step.
// R6: coalesced chunk map: consecutive lanes -> consecutive k-chunks of one row;
//     each 4-lane group consumes one full 64B line (XOR swizzle folded into the
//     source k-chunk, bijective per row). 4x fewer L2 requests per instr. LDS
//     layout [row][32] row-major; frag read cc = quad ^ (row&3) -> 2-way max
//     bank access (free). MFMA/epilogue unchanged.

typedef float v4f __attribute__((ext_vector_type(4)));
typedef short short8 __attribute__((ext_vector_type(8)));
typedef unsigned short us4 __attribute__((ext_vector_type(4)));

#define BM 128
#define BN 128

__device__ __forceinline__ unsigned short f2bf(float f) {
  unsigned int u = __builtin_bit_cast(unsigned int, f);
  u += 0x7fffu + ((u >> 16) & 1u);   // round-to-nearest-even
  return (unsigned short)(u >> 16);
}

__device__ __forceinline__ void gload_lds16(const void* g, void* l) {
  __builtin_amdgcn_global_load_lds((const __attribute__((address_space(1))) void*)g,
                                   (__attribute__((address_space(3))) void*)l, 16, 0, 0);
}

// token (g*64+n) -> source/dest pixel index (b*128+i)*128+j  (roll + window + dilation)
__device__ __forceinline__ int tok2pix(int tok) {
  int g = tok >> 6, n = tok & 63;
  int b = g >> 8, rem = g & 255;
  int d = rem & 3, bw = rem >> 2;
  int wh = bw >> 3, ww = bw & 7;
  int ph = n >> 3, pw = n & 7;
  int ii = (wh * 16 + 2 * ph + (d >> 1) + 4) & 127;
  int jj = (ww * 16 + 2 * pw + (d & 1) + 4) & 127;
  return (b * 128 + ii) * 128 + jj;
}

__global__ __launch_bounds__(256) void prep_kernel(
    const float* __restrict__ qv_w, const float* __restrict__ k_w,
    const float* __restrict__ proj_w,
    unsigned short* __restrict__ qv_wt, unsigned short* __restrict__ k_wt,
    unsigned short* __restrict__ proj_wt,
    float* __restrict__ rope_cos, float* __restrict__ rope_sin) {
  int tid = blockIdx.x * 256 + threadIdx.x;
  if (tid < 524288) {                       // qv_wt[c][k] = qv_w[k][c]
    int c = tid >> 9, k = tid & 511;
    qv_wt[tid] = f2bf(qv_w[k * 1024 + c]);
  } else if (tid < 786432) {                // k_wt[c][k] = k_w[k][c]
    int t = tid - 524288;
    int c = t >> 9, k = t & 511;
    k_wt[t] = f2bf(k_w[k * 512 + c]);
  } else if (tid < 1048576) {               // proj_wt[c][k] = proj_w[k][c]
    int t = tid - 786432;
    int c = t >> 9, k = t & 511;
    proj_wt[t] = f2bf(proj_w[k * 512 + c]);
  } else if (tid < 1048576 + 2048) {        // rope tables: [(ph*8+pw)*32 + t]
    int t = tid - 1048576;
    int pos = t >> 5, tt = t & 31;
    int ph = pos >> 3, pw = pos & 7;
    float e = (float)(tt & 15) * (1.0f / 16.0f);
    float inv = powf(10000.0f, -e);
    float ang = (float)(tt < 16 ? ph : pw) * inv;
    rope_cos[t] = cosf(ang);
    rope_sin[t] = sinf(ang);
  }
}

// Streaming fp32 -> bf16 WITH token gather: out[tok][c] = bf16(in[tok2pix(tok)][c]).
// 64 consecutive threads handle one token row: read 2KB contiguous fp32, write 1KB
// contiguous bf16 -> full BW both sides; the GEMM then reads A fully linearly.
__global__ __launch_bounds__(256) void convert_kernel(
    const float* __restrict__ in, unsigned short* __restrict__ out) {
  unsigned int stride = gridDim.x * 256u;
  for (unsigned int i = blockIdx.x * 256u + threadIdx.x; i < 4194304u; i += stride) {
    int tok = (int)(i >> 6), c8 = (int)(i & 63) * 8;
    size_t src = (size_t)tok2pix(tok) * 512 + c8;
    v4f t0 = *(const v4f*)(in + src);
    v4f t1 = *(const v4f*)(in + src + 4);
    short8 w;
    w[0] = (short)f2bf(t0[0]); w[1] = (short)f2bf(t0[1]);
    w[2] = (short)f2bf(t0[2]); w[3] = (short)f2bf(t0[3]);
    w[4] = (short)f2bf(t1[0]); w[5] = (short)f2bf(t1[1]);
    w[6] = (short)f2bf(t1[2]); w[7] = (short)f2bf(t1[3]);
    *(short8*)(out + (size_t)tok * 512 + c8) = w;
  }
}

// MODE 0: A = xg (bf16 token-order), Wt = qv_wt: q->rope*scale->Qbuf, v->Vbuf(T)
// MODE 1: A = crossg (bf16 token-order), Wt = k_wt: rope->Kbuf
// MODE 2: A = Obuf (bf16 token-order), Wt = proj_wt: +bias, scatter fp32 -> d_out
template <int MODE>
__global__ __launch_bounds__(256) void gemm_kernel(
    const unsigned short* __restrict__ Ap, const unsigned short* __restrict__ Wt,
    const float* __restrict__ bias, void* __restrict__ out0,
    void* __restrict__ out1, const float* __restrict__ rope_cos,
    const float* __restrict__ rope_sin) {
  // LDS: double-buffered [row][32] row-major (64B rows). Chunk (row,cc) holds
  // global k-chunk cc ^ (row&3) (XOR swizzle baked into the per-lane SOURCE addr;
  // LDS dest linear). Frag read: kc=quad lives at cc = quad ^ (row&3).
  __shared__ __attribute__((aligned(16))) unsigned short As[2][4096];
  __shared__ __attribute__((aligned(16))) unsigned short Bs[2][4096];
  int tid = threadIdx.x;

  // Block->tile remap: XCD-chunked (bijective, nwg%8==0) with bn FASTEST inside a
  // chunk, so blocks sharing one A-tile run back-to-back on the SAME XCD (L2 reuse).
  constexpr int NBN = (MODE == 0) ? 8 : 4;           // output col-tiles
  constexpr int NWG = 512 * NBN;
  constexpr int CPX = NWG / 8;                       // chunk per XCD
  int lin = blockIdx.x;
  int wgid = (lin & 7) * CPX + (lin >> 3);
  int bm = wgid / NBN;
  int bn = wgid % NBN;

  int lane = tid & 63, wid = tid >> 6;
  int wm = (wid & 1) * 64, wn = (wid >> 1) * 64;
  int l15 = lane & 15, quad = lane >> 4;

  // Staging chunk c = i*256 + tid -> (row = c>>2, cc = c&3). Consecutive lanes =
  // consecutive cc of one row: each 4-lane group reads one FULL 64B line (cc_src
  // is a permutation of 0..3 within the row) -> fully coalesced. LDS chunk c at
  // byte c*16 = [row][cc] row-major.
  const unsigned short* pa[2];
  const unsigned short* pb[2];
  int lOff[2];   // wave-uniform LDS element base (hardware adds lane*16B)
#pragma unroll
  for (int i = 0; i < 2; i++) {
    int c = i * 256 + tid;
    int row = c >> 2, cc = c & 3;
    int ccs = cc ^ (row & 3);          // pre-swizzled source k-chunk
    pa[i] = Ap + (size_t)(bm * BM + row) * 512 + ccs * 8;
    pb[i] = Wt + (size_t)(bn * BN + row) * 512 + ccs * 8;
    lOff[i] = (i * 256 + wid * 64) * 8;
  }

  v4f acc[4][4];
#pragma unroll
  for (int i = 0; i < 4; i++)
#pragma unroll
    for (int j = 0; j < 4; j++) acc[i][j] = (v4f){0.f, 0.f, 0.f, 0.f};

  // prologue: stage tile 0 into buffer 0
#pragma unroll
  for (int i = 0; i < 2; i++) {
    gload_lds16(pa[i], &As[0][lOff[i]]);
    gload_lds16(pb[i], &Bs[0][lOff[i]]);
  }
  __syncthreads();   // drains vmcnt -> tile 0 visible

  int cur = 0;
  for (int t = 0; t < 16; ++t) {
    if (t < 15) {
      int k0 = (t + 1) * 32;
      int nxt = cur ^ 1;
#pragma unroll
      for (int i = 0; i < 2; i++) {
        gload_lds16(pa[i] + k0, &As[nxt][lOff[i]]);
        gload_lds16(pb[i] + k0, &Bs[nxt][lOff[i]]);
      }
    }
    short8 af[4], bfr[4];
#pragma unroll
    for (int i = 0; i < 4; i++) {
      int r = wm + i * 16 + l15;
      af[i] = *(const short8*)(&As[cur][(r * 4 + (quad ^ (l15 & 3))) << 3]);
    }
#pragma unroll
    for (int j = 0; j < 4; j++) {
      int r = wn + j * 16 + l15;
      bfr[j] = *(const short8*)(&Bs[cur][(r * 4 + (quad ^ (l15 & 3))) << 3]);
    }
#pragma unroll
    for (int i = 0; i < 4; i++)
#pragma unroll
      for (int j = 0; j < 4; j++)
        acc[i][j] = __builtin_amdgcn_mfma_f32_16x16x32_bf16(af[i], bfr[j], acc[i][j], 0, 0, 0);
    __syncthreads();   // drains next tile's prefetch; protects buf reuse
    cur ^= 1;
  }

  // Epilogue. C/D layout: row = quad*4+reg (A-rows = tokens), col = lane&15 (B-rows = out channel)
#pragma unroll
  for (int j = 0; j < 4; j++) {
    int col = bn * BN + wn + j * 16 + l15;
    float bv = bias[col];
    int which = col >> 9;            // wave-uniform
    int h = (col >> 6) & 7;
    int hd = col & 63;
#pragma unroll
    for (int i = 0; i < 4; i++) {
      int tok0 = bm * BM + wm + i * 16 + quad * 4;
      if (MODE == 0 && which == 1) {
        // V stored transposed: [g][h][hd][n] — 4 consecutive n per lane -> one 8B store
        int g = tok0 >> 6, n0 = tok0 & 63;   // quad*4-aligned, no wrap across r
        us4 wv;
#pragma unroll
        for (int r = 0; r < 4; r++) wv[r] = f2bf(acc[i][j][r] + bv);
        *(us4*)((unsigned short*)out1 + ((((g * 8 + h) * 64 + hd) << 6) + n0)) = wv;
      } else if (MODE == 2) {
#pragma unroll
        for (int r = 0; r < 4; r++)
          ((float*)out0)[(size_t)tok2pix(tok0 + r) * 512 + col] = acc[i][j][r] + bv;
      } else {
        // Q (MODE 0) or K (MODE 1): rope, then store [g][h][n][hd]
#pragma unroll
        for (int r = 0; r < 4; r++) {
          int tok = tok0 + r;
          int g = tok >> 6, n = tok & 63;
          float val = acc[i][j][r] + bv;
          float part = __shfl_xor(val, 1); // rope pair partner (col^1)
          int ti = (n << 5) + (hd >> 1);
          float c = rope_cos[ti], s = rope_sin[ti];
          float o = (hd & 1) ? (part * s + val * c) : (val * c - part * s);
          if (MODE == 0) o *= 0.125f;      // HD^-0.5
          ((unsigned short*)out0)[(((g * 8 + h) * 64 + n) << 6) + hd] = f2bf(o);
        }
      }
    }
  }
}

// One block per (window-group g, head h). N=64 tokens, HD=64.
__global__ __launch_bounds__(256) void attn_kernel(
    const unsigned short* __restrict__ Qbuf, const unsigned short* __restrict__ Kbuf,
    const unsigned short* __restrict__ Vbuf, unsigned short* __restrict__ Obuf) {
  __shared__ __attribute__((aligned(16))) unsigned short Ps[4096]; // P, swizzled chunks
  int bid = blockIdx.x;
  int g = bid >> 3, h = bid & 7;
  int tid = threadIdx.x;
  int lane = tid & 63, w = tid >> 6;
  int l15 = lane & 15, quad = lane >> 4;
  size_t base = ((size_t)(g * 8 + h)) << 12;   // *4096 elems
  const unsigned short* Q = Qbuf + base;       // [n][hd]
  const unsigned short* K = Kbuf + base;       // [n][hd]
  const unsigned short* Vt = Vbuf + base;      // [hd][n]

  // S = (Q*scale,rope) @ (K,rope)^T ; wave w owns q-rows [w*16, w*16+16)
  v4f s[4];
#pragma unroll
  for (int j = 0; j < 4; j++) s[j] = (v4f){0.f, 0.f, 0.f, 0.f};
#pragma unroll
  for (int ki = 0; ki < 2; ki++) {
    short8 aq = *(const short8*)(Q + (w * 16 + l15) * 64 + ki * 32 + quad * 8);
#pragma unroll
    for (int j = 0; j < 4; j++) {
      short8 bk = *(const short8*)(K + (j * 16 + l15) * 64 + ki * 32 + quad * 8);
      s[j] = __builtin_amdgcn_mfma_f32_16x16x32_bf16(aq, bk, s[j], 0, 0, 0);
    }
  }

  // mask: only wh==7 windows; group by ph band (ph<4 | 4..5 | >=6), row-only dependence
  int rem = g & 255;
  bool masked_win = ((rem >> 5) == 7);
  float p[4][4]; // [j][r]
#pragma unroll
  for (int j = 0; j < 4; j++) {
    int m = j * 16 + l15;
    int pm = m >> 3;
    int gm = (int)(pm >= 4) + (int)(pm >= 6);
#pragma unroll
    for (int r = 0; r < 4; r++) {
      int row = w * 16 + quad * 4 + r;
      int pq = row >> 3;
      int gq = (int)(pq >= 4) + (int)(pq >= 6);
      float v = s[j][r];
      if (masked_win && gm != gq) v = -1e9f;
      p[j][r] = v;
    }
  }
  // softmax per row: values live on the 16 lanes of this quad (cols) x 4 j-tiles
#pragma unroll
  for (int r = 0; r < 4; r++) {
    float mx = fmaxf(fmaxf(p[0][r], p[1][r]), fmaxf(p[2][r], p[3][r]));
    mx = fmaxf(mx, __shfl_xor(mx, 1));
    mx = fmaxf(mx, __shfl_xor(mx, 2));
    mx = fmaxf(mx, __shfl_xor(mx, 4));
    mx = fmaxf(mx, __shfl_xor(mx, 8));
    float sum = 0.f;
#pragma unroll
    for (int j = 0; j < 4; j++) { p[j][r] = __expf(p[j][r] - mx); sum += p[j][r]; }
    sum += __shfl_xor(sum, 1);
    sum += __shfl_xor(sum, 2);
    sum += __shfl_xor(sum, 4);
    sum += __shfl_xor(sum, 8);
    float inv = 1.0f / sum;
    int row = w * 16 + quad * 4 + r;
#pragma unroll
    for (int j = 0; j < 4; j++) {
      int m = j * 16 + l15;
      int h8 = m >> 3;
      Ps[((h8 * 64 + (row ^ h8)) << 3) + (m & 7)] = f2bf(p[j][r] * inv);
    }
  }
  __syncthreads();

  // O = P @ V : A = P rows (this wave's), B = Vt (n=hd, k=m)
  v4f o[4];
#pragma unroll
  for (int j = 0; j < 4; j++) o[j] = (v4f){0.f, 0.f, 0.f, 0.f};
#pragma unroll
  for (int ki = 0; ki < 2; ki++) {
    int h8 = ki * 4 + quad;
    short8 ap = *(const short8*)(Ps + ((h8 * 64 + ((w * 16 + l15) ^ h8)) << 3));
#pragma unroll
    for (int j = 0; j < 4; j++) {
      short8 bv = *(const short8*)(Vt + (j * 16 + l15) * 64 + ki * 32 + quad * 8);
      o[j] = __builtin_amdgcn_mfma_f32_16x16x32_bf16(ap, bv, o[j], 0, 0, 0);
    }
  }
#pragma unroll
  for (int j = 0; j < 4; j++) {
    int hd = j * 16 + l15;
#pragma unroll
    for (int r = 0; r < 4; r++) {
      int row = w * 16 + quad * 4 + r;
      Obuf[(size_t)(g * 64 + row) * 512 + h * 64 + hd] = f2bf(o[j][r]);
    }
  }
}

extern "C" void kernel_launch(void* const* d_in, const int* in_sizes, int n_in,
                              void* d_out, int out_size, void* d_ws, size_t ws_size,
                              hipStream_t stream) {
  const float* x      = (const float*)d_in[0];
  const float* cross  = (const float*)d_in[1];
  const float* qv_w   = (const float*)d_in[2];
  const float* qv_b   = (const float*)d_in[3];
  const float* k_w    = (const float*)d_in[4];
  const float* k_b    = (const float*)d_in[5];
  const float* proj_w = (const float*)d_in[6];
  const float* proj_b = (const float*)d_in[7];

  char* ws = (char*)d_ws;
  const size_t MB = 1024 * 1024;
  unsigned short* Qbuf = (unsigned short*)(ws);
  unsigned short* Kbuf = (unsigned short*)(ws + 64 * MB);
  unsigned short* Vbuf = (unsigned short*)(ws + 128 * MB);
  unsigned short* Obuf = (unsigned short*)(ws + 192 * MB);
  unsigned short* qv_wt = (unsigned short*)(ws + 256 * MB);
  unsigned short* k_wt = qv_wt + 1024 * 512;
  unsigned short* proj_wt = k_wt + 512 * 512;
  float* rope_cos = (float*)(proj_wt + 512 * 512);
  float* rope_sin = rope_cos + 2048;
  unsigned short* cvt = Obuf;   // Obuf region is dead until attn -> holds bf16 inputs

  prep_kernel<<<4104, 256, 0, stream>>>(qv_w, k_w, proj_w, qv_wt, k_wt, proj_wt,
                                        rope_cos, rope_sin);
  convert_kernel<<<2048, 256, 0, stream>>>(x, cvt);
  gemm_kernel<0><<<4096, 256, 0, stream>>>(cvt, qv_wt, qv_b, Qbuf, Vbuf,
                                           rope_cos, rope_sin);
  convert_kernel<<<2048, 256, 0, stream>>>(cross, cvt);
  gemm_kernel<1><<<2048, 256, 0, stream>>>(cvt, k_wt, k_b, Kbuf, nullptr,
                                           rope_cos, rope_sin);
  attn_kernel<<<8192, 256, 0, stream>>>(Qbuf, Kbuf, Vbuf, Obuf);
  gemm_kernel<2><<<2048, 256, 0, stream>>>(Obuf, proj_wt, proj_b, d_out, nullptr,
                                           rope_cos, rope_sin);
}